// Round 9
// baseline (57067.120 us; speedup 1.0000x reference)
//
#include <hip/hip_runtime.h>
#include <stdint.h>

// LSTM final-h. B=128, T=1024, I=256, H=512. Inputs fp32, output fp32.
// R16: MEASUREMENT ROUND. R14 falsified CU-scaling; R15 falsified the
// serial-latency-chain theory (deleting 2 LLC round trips + 1 barrier:
// 5.08 -> 5.32ms, no change). Per pre-commitment, this round ablates
// instead of guessing: alongside the UNCHANGED R15 kernel (launched
// last; produces the real output), two diagnostic kernels run on
// scratch workspace, each 8 repeats of the full 1024-step loop so they
// appear in the rocprof top-5 table:
//  - lstm_floor:     per-step work identical to R15 (x prefetch, x-MFMA,
//                    4x LLC h-loads + vmcnt drain, LDS stage, barrier,
//                    48 h-MFMA, gates, WT stores) but NO tag-poll / no
//                    inter-block waiting. = intra-block chain floor.
//  - lstm_floor_noh: same minus the per-step LLC h-loads (register
//                    recycle, anti-hoist asm). = floor without h-load
//                    latency.
// Reading: floor/step = row_dur/8192. floor>=4us => chain-bound;
// <=1.5us => sync/skew ~70% of the 5.14us step; floor-floor_noh =
// h-LLC-load latency term. Real kernel expected unchanged ~5.3ms.

#define Bsz 128
#define Tsz 1024
#define Isz 256
#define Hsz 512
#define NBLK 128      // 8 domains x 16 blocks
#define NTHREADS 512  // 8 waves
#define FREPS 8       // ablation repeat factor

typedef __attribute__((ext_vector_type(8))) short short8;
typedef __attribute__((ext_vector_type(4))) float float4v;
typedef __attribute__((ext_vector_type(4))) unsigned int uint4v;

__device__ __forceinline__ float b2f(unsigned short u) {
  union { float f; unsigned int i; } v; v.i = ((unsigned int)u) << 16; return v.f;
}
__device__ __forceinline__ unsigned short f2b(float f) {
  unsigned int u = __float_as_uint(f);
  return (unsigned short)((u + 0x7fffu + ((u >> 16) & 1u)) >> 16);
}
__device__ __forceinline__ float sigmf(float x) { return 1.0f / (1.0f + __expf(-x)); }
__device__ __forceinline__ float tanhf_fast(float x) {
  float e = __expf(-2.0f * fabsf(x));
  float t = (1.0f - e) / (1.0f + e);
  return copysignf(t, x);
}
__device__ __forceinline__ short8 cvt8r(float4v u, float4v v) {
  short8 r;
  r[0] = (short)f2b(u[0]); r[1] = (short)f2b(u[1]);
  r[2] = (short)f2b(u[2]); r[3] = (short)f2b(u[3]);
  r[4] = (short)f2b(v[0]); r[5] = (short)f2b(v[1]);
  r[6] = (short)f2b(v[2]); r[7] = (short)f2b(v[3]);
  return r;
}
// HW packed fp32->bf16 (RNE, same rounding as f2b). No builtin on gfx950.
__device__ __forceinline__ unsigned int cvtpk(float a, float b) {
  unsigned int r;
  asm("v_cvt_pk_bf16_f32 %0, %1, %2" : "=v"(r) : "v"(a), "v"(b));
  return r;
}
__device__ __forceinline__ short8 cvt8pk(float4v u, float4v v) {
  union { unsigned int d[4]; short8 s; } r;
  r.d[0] = cvtpk(u[0], u[1]);
  r.d[1] = cvtpk(u[2], u[3]);
  r.d[2] = cvtpk(v[0], v[1]);
  r.d[3] = cvtpk(v[2], v[3]);
  return r.s;
}

#define MFMA(A, B, C) __builtin_amdgcn_mfma_f32_16x16x32_bf16((A), (B), (C), 0, 0, 0)

#define LLD(dst, base, OFFB)                                              \
  asm volatile("global_load_dwordx4 %0, %1, off offset:" OFFB " sc0 sc1"  \
               : "=v"(dst) : "v"(base))
#define XLD(dst, base, OFFB)                                              \
  asm volatile("global_load_dwordx4 %0, %1, off offset:" OFFB             \
               : "=v"(dst) : "v"(base))
#define VMW(N)                                                            \
  do { asm volatile("s_waitcnt vmcnt(" #N ")" ::: "memory");              \
       __builtin_amdgcn_sched_barrier(0); } while (0)

// ---- shared per-thread setup (identical across the 3 kernels) ----
#define COMMON_SETUP                                                      \
  const int tid  = threadIdx.x;                                           \
  const int wid  = tid >> 6;                                              \
  const int lane = tid & 63;                                              \
  const int l15  = lane & 15;                                             \
  const int kq   = lane >> 4;                                             \
  const int qg   = l15 >> 2;                                              \
  const int ug   = l15 & 3;                                               \
  const int blk  = blockIdx.x;                                            \
  const int dom  = blk >> 4;                                              \
  const int bi   = blk & 15;                                              \
  const int col  = qg * Hsz + bi * 32 + wid * 4 + ug;                     \
  const int rowbase = dom * 16;                                           \
  short8 wx[8], whhhi[16], whhlo[16];                                     \
  {                                                                       \
    const float* p = wih + (size_t)col * Isz + kq * 8;                    \
    _Pragma("unroll")                                                     \
    for (int ks = 0; ks < 8; ++ks) {                                      \
      float4v u0 = *(const float4v*)(p + ks * 32);                        \
      float4v u1 = *(const float4v*)(p + ks * 32 + 4);                    \
      wx[ks] = cvt8r(u0, u1);                                             \
    }                                                                     \
  }                                                                       \
  {                                                                       \
    const float* p = whh + (size_t)col * Hsz + kq * 8;                    \
    _Pragma("unroll")                                                     \
    for (int ks = 0; ks < 16; ++ks) {                                     \
      float4v u0 = *(const float4v*)(p + ks * 32);                        \
      float4v u1 = *(const float4v*)(p + ks * 32 + 4);                    \
      short8 hi = cvt8r(u0, u1);                                          \
      short8 lo;                                                          \
      _Pragma("unroll")                                                   \
      for (int e = 0; e < 4; ++e) {                                       \
        lo[e]     = (short)f2b(u0[e] - b2f((unsigned short)hi[e]));       \
        lo[e + 4] = (short)f2b(u1[e] - b2f((unsigned short)hi[e + 4]));   \
      }                                                                   \
      whhhi[ks] = hi; whhlo[ks] = lo;                                     \
    }                                                                     \
  }                                                                       \
  const float biasC = bih[col] + bhh[col];                                \
  const int srow = tid & 15;                                              \
  const int grow = rowbase + srow;                                        \
  const int cidx = tid >> 4;                                              \
  const int f1   = (cidx >> 1) * 64 + (cidx & 1) * 32 + srow;             \
  const float* xsrc0 = x + (size_t)grow * (Tsz * Isz) + cidx * 8;         \
  const int growo = rowbase + kq * 4 + qg;                                \
  const int hunit = bi * 32 + wid * 4 + ug;

#define UNPACK_AND_STAGE(pl)                                              \
  {                                                                       \
    short8 h0, h1, l0, l1;                                                \
    _Pragma("unroll")                                                     \
    for (int e = 0; e < 4; ++e) {                                         \
      h0[e]     = (short)(d0[e] & 0xffffu); l0[e]     = (short)(d0[e] >> 16); \
      h0[e + 4] = (short)(d1[e] & 0xffffu); l0[e + 4] = (short)(d1[e] >> 16); \
      h1[e]     = (short)(d2[e] & 0xffffu); l1[e]     = (short)(d2[e] >> 16); \
      h1[e + 4] = (short)(d3[e] & 0xffffu); l1[e + 4] = (short)(d3[e] >> 16); \
    }                                                                     \
    hhi_pl[pl][f1]      = h0;  hlo_pl[pl][f1]      = l0;                  \
    hhi_pl[pl][f1 + 16] = h1;  hlo_pl[pl][f1 + 16] = l1;                  \
  }

#define HMFMA_LOOP(pl)                                                    \
  _Pragma("unroll")                                                       \
  for (int ks = 0; ks < 16; ++ks) {                                       \
    short8 ha = hhi_pl[pl][ks * 64 + lane];                               \
    short8 la = hlo_pl[pl][ks * 64 + lane];                               \
    accm = MFMA(ha, whhhi[ks], accm);                                     \
    accc = MFMA(ha, whhlo[ks], accc);                                     \
    accc = MFMA(la, whhhi[ks], accc);                                     \
  }

#define GATES_AND_STORE(OUTW)                                             \
  float v0 = accm[0] + accc[0] + biasC;                                   \
  float v1 = accm[1] + accc[1] + biasC;                                   \
  float v2 = accm[2] + accc[2] + biasC;                                   \
  float v3 = accm[3] + accc[3] + biasC;                                   \
  int k1 = qg ^ 1, k2 = qg ^ 2, k3 = qg ^ 3;                              \
  float s0 = (qg == 0) ? v0 : (qg == 1) ? v1 : (qg == 2) ? v2 : v3;       \
  float s1 = (k1 == 0) ? v0 : (k1 == 1) ? v1 : (k1 == 2) ? v2 : v3;       \
  float s2 = (k2 == 0) ? v0 : (k2 == 1) ? v1 : (k2 == 2) ? v2 : v3;       \
  float s3 = (k3 == 0) ? v0 : (k3 == 1) ? v1 : (k3 == 2) ? v2 : v3;       \
  float r4  = __shfl_xor(s1, 4, 64);                                      \
  float r8  = __shfl_xor(s2, 8, 64);                                      \
  float r12 = __shfl_xor(s3, 12, 64);                                     \
  float gi = (qg == 0) ? s0 : (qg == 1) ? r4 : (qg == 2) ? r8 : r12;      \
  float gf = (qg == 1) ? s0 : (qg == 0) ? r4 : (qg == 3) ? r8 : r12;      \
  float gG = (qg == 2) ? s0 : (qg == 3) ? r4 : (qg == 0) ? r8 : r12;      \
  float go = (qg == 3) ? s0 : (qg == 2) ? r4 : (qg == 1) ? r8 : r12;      \
  float ig = sigmf(gi);                                                   \
  float fg = sigmf(gf);                                                   \
  float gg = tanhf_fast(gG);                                              \
  float og = sigmf(go);                                                   \
  float c  = fg * cstv + ig * gg;                                         \
  cstv = c;                                                               \
  float hv = og * tanhf_fast(c);                                          \
  if (t == Tsz - 1) {                                                     \
    (OUTW)[(size_t)growo * Hsz + hunit] = hv;                             \
  } else {                                                                \
    unsigned short hi16 = f2b(hv);                                        \
    unsigned short lo16 = f2b(hv - b2f(hi16));                            \
    lo16 = (unsigned short)((lo16 & 0xFFFEu) |                            \
                            ((unsigned int)((t + 1) >> 1) & 1u));         \
    unsigned int pk = (unsigned int)hi16 | ((unsigned int)lo16 << 16);    \
    unsigned int* pp = (par ? b0 : b1) + (size_t)growo * Hsz + hunit;     \
    asm volatile("global_store_dword %0, %1, off sc0 sc1"                 \
                 :: "v"(pp), "v"(pk) : "memory");                         \
  }

// ================== REAL KERNEL: byte-identical to R15 ==================
__global__ __launch_bounds__(NTHREADS, 2) void lstm_persistent(
    const float* __restrict__ x, const float* __restrict__ wih,
    const float* __restrict__ whh, const float* __restrict__ bih,
    const float* __restrict__ bhh, float* __restrict__ out,
    unsigned int* __restrict__ b0, unsigned int* __restrict__ b1)
{
  __shared__ short8 hhi_pl[2][1024];
  __shared__ short8 hlo_pl[2][1024];
  __shared__ short8 x_pl[2][512];
  COMMON_SETUP
  {
    float4v u0, u1;
    XLD(u0, xsrc0, "0"); XLD(u1, xsrc0, "16");
    VMW(0);
    x_pl[0][tid] = cvt8pk(u0, u1);
  }
  __syncthreads();
  float cstv = 0.f;

  for (int t = 0; t < Tsz; ++t) {
    const int par = t & 1;
    float4v xu0, xu1;
    const int tn = (t + 1 < Tsz) ? t + 1 : t;
    {
      const float* xp = xsrc0 + (size_t)tn * Isz;
      XLD(xu0, xp, "0"); XLD(xu1, xp, "16");
    }
    float4v accm = {0.f, 0.f, 0.f, 0.f};
    float4v accc = {0.f, 0.f, 0.f, 0.f};
#pragma unroll
    for (int ks = 0; ks < 8; ++ks) {
      short8 xa = x_pl[par][ks * 64 + lane];
      accm = MFMA(xa, wx[ks], accm);
    }
    const unsigned int* hsrc = (par ? b1 : b0) + (size_t)grow * Hsz + cidx * 16;
    const unsigned int tagm = ((unsigned int)((t >> 1) & 1)) << 16;
    uint4v d0, d1, d2, d3;
    {
      int guard = 0;
      for (;;) {
        LLD(d0, hsrc, "0");  LLD(d1, hsrc, "16");
        LLD(d2, hsrc, "32"); LLD(d3, hsrc, "48");
        VMW(0);
        unsigned int a =
            (d0[0] ^ tagm) | (d0[1] ^ tagm) | (d0[2] ^ tagm) | (d0[3] ^ tagm) |
            (d1[0] ^ tagm) | (d1[1] ^ tagm) | (d1[2] ^ tagm) | (d1[3] ^ tagm) |
            (d2[0] ^ tagm) | (d2[1] ^ tagm) | (d2[2] ^ tagm) | (d2[3] ^ tagm) |
            (d3[0] ^ tagm) | (d3[1] ^ tagm) | (d3[2] ^ tagm) | (d3[3] ^ tagm);
        if (!(a & 0x00010000u)) break;
        __builtin_amdgcn_s_sleep(1);
        if (++guard > (1 << 20)) break;
      }
    }
    if (t + 1 < Tsz) x_pl[par ^ 1][tid] = cvt8pk(xu0, xu1);
    UNPACK_AND_STAGE(par)
    __syncthreads();
    HMFMA_LOOP(par)
    GATES_AND_STORE(out)
  }
}

// ============ ABLATION 1: no inter-block sync (chain floor) ============
__global__ __launch_bounds__(NTHREADS, 2) void lstm_floor(
    const float* __restrict__ x, const float* __restrict__ wih,
    const float* __restrict__ whh, const float* __restrict__ bih,
    const float* __restrict__ bhh, float* __restrict__ out,
    unsigned int* __restrict__ b0, unsigned int* __restrict__ b1)
{
  __shared__ short8 hhi_pl[2][1024];
  __shared__ short8 hlo_pl[2][1024];
  __shared__ short8 x_pl[2][512];
  COMMON_SETUP
  {
    float4v u0, u1;
    XLD(u0, xsrc0, "0"); XLD(u1, xsrc0, "16");
    VMW(0);
    x_pl[0][tid] = cvt8pk(u0, u1);
  }
  __syncthreads();
  float cstv = 0.f;

  for (int rep = 0; rep < FREPS; ++rep)
  for (int t = 0; t < Tsz; ++t) {
    const int par = t & 1;
    float4v xu0, xu1;
    const int tn = (t + 1 < Tsz) ? t + 1 : t;
    {
      const float* xp = xsrc0 + (size_t)tn * Isz;
      XLD(xu0, xp, "0"); XLD(xu1, xp, "16");
    }
    float4v accm = {0.f, 0.f, 0.f, 0.f};
    float4v accc = {0.f, 0.f, 0.f, 0.f};
#pragma unroll
    for (int ks = 0; ks < 8; ++ks) {
      short8 xa = x_pl[par][ks * 64 + lane];
      accm = MFMA(xa, wx[ks], accm);
    }
    const unsigned int* hsrc = (par ? b1 : b0) + (size_t)grow * Hsz + cidx * 16;
    uint4v d0, d1, d2, d3;
    // same loads + drain as real, but NO tag check / no waiting
    LLD(d0, hsrc, "0");  LLD(d1, hsrc, "16");
    LLD(d2, hsrc, "32"); LLD(d3, hsrc, "48");
    VMW(0);
    if (t + 1 < Tsz) x_pl[par ^ 1][tid] = cvt8pk(xu0, xu1);
    UNPACK_AND_STAGE(par)
    __syncthreads();
    HMFMA_LOOP(par)
    GATES_AND_STORE(out)
  }
}

// ====== ABLATION 2: no sync AND no per-step h LLC loads ======
__global__ __launch_bounds__(NTHREADS, 2) void lstm_floor_noh(
    const float* __restrict__ x, const float* __restrict__ wih,
    const float* __restrict__ whh, const float* __restrict__ bih,
    const float* __restrict__ bhh, float* __restrict__ out,
    unsigned int* __restrict__ b0, unsigned int* __restrict__ b1)
{
  __shared__ short8 hhi_pl[2][1024];
  __shared__ short8 hlo_pl[2][1024];
  __shared__ short8 x_pl[2][512];
  COMMON_SETUP
  uint4v d0, d1, d2, d3;
  {
    float4v u0, u1;
    XLD(u0, xsrc0, "0"); XLD(u1, xsrc0, "16");
    const unsigned int* hsrc = b0 + (size_t)grow * Hsz + cidx * 16;
    LLD(d0, hsrc, "0");  LLD(d1, hsrc, "16");
    LLD(d2, hsrc, "32"); LLD(d3, hsrc, "48");
    VMW(0);
    x_pl[0][tid] = cvt8pk(u0, u1);
  }
  __syncthreads();
  float cstv = 0.f;

  for (int rep = 0; rep < FREPS; ++rep)
  for (int t = 0; t < Tsz; ++t) {
    const int par = t & 1;
    float4v xu0, xu1;
    const int tn = (t + 1 < Tsz) ? t + 1 : t;
    {
      const float* xp = xsrc0 + (size_t)tn * Isz;
      XLD(xu0, xp, "0"); XLD(xu1, xp, "16");
    }
    float4v accm = {0.f, 0.f, 0.f, 0.f};
    float4v accc = {0.f, 0.f, 0.f, 0.f};
#pragma unroll
    for (int ks = 0; ks < 8; ++ks) {
      short8 xa = x_pl[par][ks * 64 + lane];
      accm = MFMA(xa, wx[ks], accm);
    }
    // keep d0..d3 loop-carried so unpack VALU work can't be hoisted
    asm volatile("" : "+v"(d0), "+v"(d1), "+v"(d2), "+v"(d3));
    VMW(0);  // drains the 2 x loads (+ prev stores), mirroring real timing
    if (t + 1 < Tsz) x_pl[par ^ 1][tid] = cvt8pk(xu0, xu1);
    UNPACK_AND_STAGE(par)
    __syncthreads();
    HMFMA_LOOP(par)
    GATES_AND_STORE(out)
  }
}

extern "C" void kernel_launch(void* const* d_in, const int* in_sizes, int n_in,
                              void* d_out, int out_size, void* d_ws, size_t ws_size,
                              hipStream_t stream) {
  if (n_in < 5) return;
  long long s0 = in_sizes[0], s1 = in_sizes[1], s2 = in_sizes[2],
            s3 = in_sizes[3], s4 = in_sizes[4];
  if (!(s1 > 0 && s3 > 0 && s0 == 64 * s1 && s2 == 2 * s1 &&
        s1 == 256 * s3 && s3 == s4)) return;

  const float* x   = (const float*)d_in[0];
  const float* wih = (const float*)d_in[1];
  const float* whh = (const float*)d_in[2];
  const float* bih = (const float*)d_in[3];
  const float* bhh = (const float*)d_in[4];
  float* out = (float*)d_out;

  char* ws = (char*)d_ws;
  const size_t HB = (size_t)Bsz * Hsz * 4;         // 256 KB per packed h buffer
  unsigned int* hb0 = (unsigned int*)ws;
  unsigned int* hb1 = (unsigned int*)(ws + HB);

  hipMemsetAsync(hb0, 0x00, HB, stream);
  hipMemsetAsync(hb1, 0x01, HB, stream);

  // diagnostics only if workspace has room for scratch buffers
  if (ws_size >= 6 * HB) {
    unsigned int* shb0 = (unsigned int*)(ws + 2 * HB);
    unsigned int* shb1 = (unsigned int*)(ws + 3 * HB);
    float*        dout = (float*)(ws + 4 * HB);    // 256 KB dummy out
    hipMemsetAsync(shb0, 0x00, 3 * HB, stream);
    hipLaunchKernelGGL(lstm_floor_noh, dim3(NBLK), dim3(NTHREADS), 0, stream,
                       x, wih, whh, bih, bhh, dout, shb0, shb1);
    hipLaunchKernelGGL(lstm_floor, dim3(NBLK), dim3(NTHREADS), 0, stream,
                       x, wih, whh, bih, bhh, dout, shb0, shb1);
  }

  hipLaunchKernelGGL(lstm_persistent, dim3(NBLK), dim3(NTHREADS), 0, stream,
                     x, wih, whh, bih, bhh, out, hb0, hb1);
}

// Round 10
// 4184.031 us; speedup vs baseline: 13.6393x; 13.6393x over previous
//
#include <hip/hip_runtime.h>
#include <stdint.h>

// LSTM final-h. B=128, T=1024, I=256, H=512. Inputs fp32, output fp32.
// R17: fp16 everywhere — delete the compensation machinery.
// R16 ablation: floor (no inter-block sync) = 4.07us/step vs real
// 5.14us/step => chain-bound (sync only ~21%). Floor itself is
// latency-bound (active-CU MfmaUtil ~18%): the hi/lo-bf16 compensation
// makes a 32-deep dependent MFMA chain (accc) + 48 h-MFMAs + unpack VALU
// + big stage. The x-path is PLAIN bf16 (2^-8 rel) and sets the 1.95e-3
// error floor, so compensating h/W to ~2^-16 was overkill: fp16 (2^-11)
// everywhere is MORE accurate than the current x-path and:
//  - h-MFMAs 48 -> 16 per wave-step (mfma_f32_16x16x32_f16, fp32 acc);
//    dependent chains 32 -> 8 deep (acc0/acc1 split).
//  - staged shorts ARE fragments: unpack phase deleted.
//  - h buffers fp16 [128][512] (128KB): stage 16KB/block/step (was 32),
//    broadcast 2MB/step, h store = 1 short/lane.
//  - freshness tag rides in each fp16's LSB (2^-11 perturbation);
//    hb1 memset 0x01 -> virgin tag 1; expected tag (t>>1)&1.
//  - h poll-loads issued at step TOP (oldest in vmcnt FIFO): latency
//    hides under the 8 x-MFMAs; VMW(2) drains h only (x stays in
//    flight); x drained after h staging, right before its LDS write.
// Invariants: zero cache-maintenance ops; WT sc0 sc1 h stores;
// LLC-direct sc0 sc1 stage loads; fragment-ordered LDS (0 conflicts);
// one barrier/step; R12 geometry (128 blocks x 8 waves, 8 dom x 16 blk).

#define Bsz 128
#define Tsz 1024
#define Isz 256
#define Hsz 512
#define NBLK 128      // 8 domains x 16 blocks
#define NTHREADS 512  // 8 waves

typedef __attribute__((ext_vector_type(8))) _Float16 half8;
typedef __attribute__((ext_vector_type(4))) float float4v;
typedef __attribute__((ext_vector_type(4))) unsigned int uint4v;

__device__ __forceinline__ float sigmf(float x) { return 1.0f / (1.0f + __expf(-x)); }
__device__ __forceinline__ float tanhf_fast(float x) {
  float e = __expf(-2.0f * fabsf(x));
  float t = (1.0f - e) / (1.0f + e);
  return copysignf(t, x);
}
// 8x fp32 -> fp16 (RNE scalar converts)
__device__ __forceinline__ half8 cvt8h(float4v u, float4v v) {
  half8 r;
  r[0] = (_Float16)u[0]; r[1] = (_Float16)u[1];
  r[2] = (_Float16)u[2]; r[3] = (_Float16)u[3];
  r[4] = (_Float16)v[0]; r[5] = (_Float16)v[1];
  r[6] = (_Float16)v[2]; r[7] = (_Float16)v[3];
  return r;
}

#define MFMA16(A, B, C) __builtin_amdgcn_mfma_f32_16x16x32_f16((A), (B), (C), 0, 0, 0)

// LLC-direct 16B load (coherent h path; bypass L1/L2).
#define LLD(dst, base, OFFB)                                              \
  asm volatile("global_load_dwordx4 %0, %1, off offset:" OFFB " sc0 sc1"  \
               : "=v"(dst) : "v"(base))
// Cached 16B load (x prefetch), pinned at issue point.
#define XLD(dst, base, OFFB)                                              \
  asm volatile("global_load_dwordx4 %0, %1, off offset:" OFFB             \
               : "=v"(dst) : "v"(base))
#define VMW(N)                                                            \
  do { asm volatile("s_waitcnt vmcnt(" #N ")" ::: "memory");              \
       __builtin_amdgcn_sched_barrier(0); } while (0)

__global__ __launch_bounds__(NTHREADS, 2) void lstm_persistent(
    const float* __restrict__ x,
    const float* __restrict__ wih,
    const float* __restrict__ whh,
    const float* __restrict__ bih,
    const float* __restrict__ bhh,
    float* __restrict__ out,
    unsigned short* __restrict__ hb0,   // h fp16 (LSB=tag), parity 0: [128][512]
    unsigned short* __restrict__ hb1)   // parity 1 (memset 0x01: virgin tag 1)
{
  __shared__ half8 h_pl[2][1024];      // 32 KB: h fragments f=ks*64+kq*16+row, dbuf
  __shared__ half8 x_pl[2][512];       // 16 KB: x fragments, dbuf

  const int tid  = threadIdx.x;
  const int wid  = tid >> 6;
  const int lane = tid & 63;
  const int l15  = lane & 15;
  const int kq   = lane >> 4;
  const int qg   = l15 >> 2;   // gate index 0..3 (i,f,g,o)
  const int ug   = l15 & 3;    // unit-within-4
  const int blk  = blockIdx.x;
  const int dom  = blk >> 4;   // 8 domains (16 batch rows each)
  const int bi   = blk & 15;   // block-in-domain: units bi*32 .. bi*32+31
  const int col  = qg * Hsz + bi * 32 + wid * 4 + ug;  // gate column
  const int rowbase = dom * 16;

  // ---- W into registers as fp16 B-fragments (one-time prologue) ----
  half8 wx[8], wh[16];
  {
    const float* p = wih + (size_t)col * Isz + kq * 8;
#pragma unroll
    for (int ks = 0; ks < 8; ++ks) {
      float4v u0 = *(const float4v*)(p + ks * 32);
      float4v u1 = *(const float4v*)(p + ks * 32 + 4);
      wx[ks] = cvt8h(u0, u1);
    }
  }
  {
    const float* p = whh + (size_t)col * Hsz + kq * 8;
#pragma unroll
    for (int ks = 0; ks < 16; ++ks) {
      float4v u0 = *(const float4v*)(p + ks * 32);
      float4v u1 = *(const float4v*)(p + ks * 32 + 4);
      wh[ks] = cvt8h(u0, u1);
    }
  }
  const float biasC = bih[col] + bhh[col];

  // ---- staging maps (fragment-ordered, conflict-free) ----
  const int srow = tid & 15;            // local row this thread stages
  const int grow = rowbase + srow;      // global row
  const int cidx = tid >> 4;            // 0..31: 16-unit (32B) chunk index
  const int f1   = (cidx >> 1) * 64 + (cidx & 1) * 32 + srow;  // frag; f2=f1+16
  const float* xsrc0 = x + (size_t)grow * (Tsz * Isz) + cidx * 8;

  // ---- prologue: stage x(0) ----
  {
    float4v u0, u1;
    XLD(u0, xsrc0, "0"); XLD(u1, xsrc0, "16");
    VMW(0);
    x_pl[0][tid] = cvt8h(u0, u1);   // tid == (cidx>>2)*64+(cidx&3)*16+srow
  }
  __syncthreads();

  float cstv = 0.f;                              // cell state: row kq*4+qg, unit ug
  const int growo = rowbase + kq * 4 + qg;       // output row this lane owns
  const int hunit = bi * 32 + wid * 4 + ug;      // output unit this lane owns

  for (int t = 0; t < Tsz; ++t) {
    const int par = t & 1;

    // ---- issue h(t) stage loads FIRST (oldest in FIFO): 32B of one row ----
    const unsigned short* hsrc =
        (par ? hb1 : hb0) + (size_t)grow * Hsz + cidx * 16;
    uint4v d0, d1;
    LLD(d0, hsrc, "0"); LLD(d1, hsrc, "16");

    // ---- issue x(t+1) prefetch (younger; drained after h staging) ----
    float4v xu0, xu1;
    const int tn = (t + 1 < Tsz) ? t + 1 : t;
    {
      const float* xp = xsrc0 + (size_t)tn * Isz;
      XLD(xu0, xp, "0"); XLD(xu1, xp, "16");
    }

    // ---- x-part MFMAs (cover the h-load LLC latency) ----
    float4v accm = {0.f, 0.f, 0.f, 0.f};
    float4v acc0 = {0.f, 0.f, 0.f, 0.f};
    float4v acc1 = {0.f, 0.f, 0.f, 0.f};
#pragma unroll
    for (int ks = 0; ks < 8; ++ks) {
      half8 xa = x_pl[par][ks * 64 + lane];
      accm = MFMA16(xa, wx[ks], accm);
    }

    // ---- h arrived? counted drain (x loads stay in flight) + tag check ----
    VMW(2);
    {
      const unsigned int expd = ((t >> 1) & 1) ? 0x00010001u : 0u;
      unsigned int a =
          ((d0[0] ^ expd) | (d0[1] ^ expd) | (d0[2] ^ expd) | (d0[3] ^ expd) |
           (d1[0] ^ expd) | (d1[1] ^ expd) | (d1[2] ^ expd) | (d1[3] ^ expd))
          & 0x00010001u;
      if (a) {                                  // stale: retry loop
        int guard = 0;
        for (;;) {
          LLD(d0, hsrc, "0"); LLD(d1, hsrc, "16");
          VMW(0);                               // x also drains here; fine
          a = ((d0[0] ^ expd) | (d0[1] ^ expd) | (d0[2] ^ expd) |
               (d0[3] ^ expd) | (d1[0] ^ expd) | (d1[1] ^ expd) |
               (d1[2] ^ expd) | (d1[3] ^ expd)) & 0x00010001u;
          if (!a) break;
          __builtin_amdgcn_s_sleep(1);
          if (++guard > (1 << 20)) break;       // fail loud, never hang
        }
      }
    }

    // ---- stage h fragments directly (staged shorts ARE fragments) ----
    {
      union { uint4v d; half8 h; } c0, c1;
      c0.d = d0; c1.d = d1;
      h_pl[par][f1]      = c0.h;
      h_pl[par][f1 + 16] = c1.h;
    }
    // x(t+1) drained (or long done): convert + write next x plane
    VMW(0);
    if (t + 1 < Tsz) x_pl[par ^ 1][tid] = cvt8h(xu0, xu1);
    __syncthreads();  // the ONLY barrier: planes ready; prev reads done

    // ---- h-part MFMAs: 16 total, two 8-deep chains ----
#pragma unroll
    for (int ks = 0; ks < 8; ++ks) {
      half8 ha = h_pl[par][ks * 64 + lane];
      half8 hb = h_pl[par][(ks + 8) * 64 + lane];
      acc0 = MFMA16(ha, wh[ks], acc0);
      acc1 = MFMA16(hb, wh[ks + 8], acc1);
    }

    // ---- gates on ALL lanes: lane owns (row kq*4+qg, unit ug) ----
    float v0 = accm[0] + acc0[0] + acc1[0] + biasC;
    float v1 = accm[1] + acc0[1] + acc1[1] + biasC;
    float v2 = accm[2] + acc0[2] + acc1[2] + biasC;
    float v3 = accm[3] + acc0[3] + acc1[3] + biasC;
    // send v[qg^m] on exchange xor(4m); receive partner's row-qg gate
    int k1 = qg ^ 1, k2 = qg ^ 2, k3 = qg ^ 3;
    float s0 = (qg == 0) ? v0 : (qg == 1) ? v1 : (qg == 2) ? v2 : v3;
    float s1 = (k1 == 0) ? v0 : (k1 == 1) ? v1 : (k1 == 2) ? v2 : v3;
    float s2 = (k2 == 0) ? v0 : (k2 == 1) ? v1 : (k2 == 2) ? v2 : v3;
    float s3 = (k3 == 0) ? v0 : (k3 == 1) ? v1 : (k3 == 2) ? v2 : v3;
    float r4  = __shfl_xor(s1, 4, 64);   // gate qg^1, row qg
    float r8  = __shfl_xor(s2, 8, 64);   // gate qg^2, row qg
    float r12 = __shfl_xor(s3, 12, 64);  // gate qg^3, row qg
    float gi = (qg == 0) ? s0 : (qg == 1) ? r4 : (qg == 2) ? r8 : r12;
    float gf = (qg == 1) ? s0 : (qg == 0) ? r4 : (qg == 3) ? r8 : r12;
    float gG = (qg == 2) ? s0 : (qg == 3) ? r4 : (qg == 0) ? r8 : r12;
    float go = (qg == 3) ? s0 : (qg == 2) ? r4 : (qg == 1) ? r8 : r12;

    float ig = sigmf(gi);
    float fg = sigmf(gf);
    float gg = tanhf_fast(gG);
    float og = sigmf(go);
    float c  = fg * cstv + ig * gg;
    cstv = c;
    float hv = og * tanhf_fast(c);

    if (t == Tsz - 1) {
      out[(size_t)growo * Hsz + hunit] = hv;     // fp32 output
    } else {
      union { _Float16 h; unsigned short u; } cv;
      cv.h = (_Float16)hv;
      // epoch tag in fp16 LSB (~2^-11 relative: under the error floor)
      cv.u = (unsigned short)((cv.u & 0xFFFEu) |
                              ((unsigned int)((t + 1) >> 1) & 1u));
      unsigned short* pp = (par ? hb0 : hb1) + (size_t)growo * Hsz + hunit;
      unsigned int sv = cv.u;
      asm volatile("global_store_short %0, %1, off sc0 sc1"
                   :: "v"(pp), "v"(sv) : "memory");
      // no drain, no flag: consumers detect freshness from the tag;
      // the store retires under next iter's VMW windows.
    }
  }
}

extern "C" void kernel_launch(void* const* d_in, const int* in_sizes, int n_in,
                              void* d_out, int out_size, void* d_ws, size_t ws_size,
                              hipStream_t stream) {
  if (n_in < 5) return;
  long long s0 = in_sizes[0], s1 = in_sizes[1], s2 = in_sizes[2],
            s3 = in_sizes[3], s4 = in_sizes[4];
  if (!(s1 > 0 && s3 > 0 && s0 == 64 * s1 && s2 == 2 * s1 &&
        s1 == 256 * s3 && s3 == s4)) return;

  const float* x   = (const float*)d_in[0];
  const float* wih = (const float*)d_in[1];
  const float* whh = (const float*)d_in[2];
  const float* bih = (const float*)d_in[3];
  const float* bhh = (const float*)d_in[4];
  float* out = (float*)d_out;

  char* ws = (char*)d_ws;
  const size_t HB = (size_t)Bsz * Hsz * 2;         // 128 KB per fp16 h buffer
  unsigned short* hb0 = (unsigned short*)ws;
  unsigned short* hb1 = (unsigned short*)(ws + HB);

  // hb0: h(0)=+0 fp16, tag 0. hb1: 0x0101 shorts -> tag 1 (virgin; can't
  // match h(1)'s expected tag 0), value ~6e-5 never used as data.
  hipMemsetAsync(hb0, 0x00, HB, stream);
  hipMemsetAsync(hb1, 0x01, HB, stream);

  hipLaunchKernelGGL(lstm_persistent, dim3(NBLK), dim3(NTHREADS), 0, stream,
                     x, wih, whh, bih, bhh, out, hb0, hb1);
}